// Round 1
// baseline (1221.666 us; speedup 1.0000x reference)
//
#include <hip/hip_runtime.h>

#define NN 128
#define NITER 300
#define NBIS 34   // reference uses 50; 34 reaches fp32-ulp convergence of tau,
                  // and w depends only on the active set + re-derived tau -> same w

// ---- DPP wave-64 reductions (VALU pipe, no LDS traffic) ----
// add: old=0 makes bound_ctrl semantics irrelevant (invalid lanes contribute 0)
template<int CTRL>
__device__ __forceinline__ float dpp0(float x) {
  return __int_as_float(__builtin_amdgcn_update_dpp(0, __float_as_int(x), CTRL, 0xF, 0xF, true));
}
// min/max: old=self so invalid lanes are a no-op either way
template<int CTRL>
__device__ __forceinline__ float dppS(float x) {
  int xi = __float_as_int(x);
  return __int_as_float(__builtin_amdgcn_update_dpp(xi, xi, CTRL, 0xF, 0xF, false));
}
__device__ __forceinline__ float bcast63(float x) {
  return __int_as_float(__builtin_amdgcn_readlane(__float_as_int(x), 63));
}
__device__ __forceinline__ float wsum(float x) {     // sum over 64 lanes -> uniform
  x += dpp0<0x111>(x);  // row_shr:1
  x += dpp0<0x112>(x);  // row_shr:2
  x += dpp0<0x114>(x);  // row_shr:4
  x += dpp0<0x118>(x);  // row_shr:8
  x += dpp0<0x142>(x);  // row_bcast15
  x += dpp0<0x143>(x);  // row_bcast31
  return bcast63(x);
}
__device__ __forceinline__ float wmin(float x) {
  x = fminf(x, dppS<0x111>(x)); x = fminf(x, dppS<0x112>(x));
  x = fminf(x, dppS<0x114>(x)); x = fminf(x, dppS<0x118>(x));
  x = fminf(x, dppS<0x142>(x)); x = fminf(x, dppS<0x143>(x));
  return bcast63(x);
}
__device__ __forceinline__ float wmax(float x) {
  x = fmaxf(x, dppS<0x111>(x)); x = fmaxf(x, dppS<0x112>(x));
  x = fmaxf(x, dppS<0x114>(x)); x = fmaxf(x, dppS<0x118>(x));
  x = fmaxf(x, dppS<0x142>(x)); x = fmaxf(x, dppS<0x143>(x));
  return bcast63(x);
}

// quad interleave: even quads -> slots 0..15, odd -> 16..31. Makes the 8-float
// (2-quad) tile reads land on 2-way bank aliasing (free, m136) instead of 4-way.
__device__ __forceinline__ int qslot(int j4) { return (j4 >> 1) + ((j4 & 1) << 4); }

__launch_bounds__(256, 4)   // 4 waves/EU -> 4 blocks/CU (LDS ~36KB allows 4)
__global__ void markowitz_kernel(const float* __restrict__ rets,
                                 const float* __restrict__ cov,
                                 const float* __restrict__ gam,
                                 const float* __restrict__ alp,
                                 float* __restrict__ out)
{
  // cq: staged C chunk (64 rows x 132 padded) reused for Q redistribution
  __shared__ __align__(16) float cq[64 * 132];
  __shared__ __align__(16) float yL[NN];
  __shared__ __align__(16) float wLs[NN];
  __shared__ float pL[2][NN];
  __shared__ __align__(16) float red[8];

  const int b    = blockIdx.x;
  const int t    = threadIdx.x;
  const int lane = t & 63;
  const int wid  = t >> 6;
  const int rh   = wid & 1;          // matvec row half
  const int ch   = wid >> 1;         // matvec col half
  const int row  = rh * 64 + lane;   // this thread's matvec row

  const float g   = gam[b];
  const float g2  = g * g;
  const float aab = fabsf(alp[b]);
  const float* cb = cov + (size_t)b * (NN * NN);

  // tile map chosen so tile-writers of phase p == fragment-readers of phase p
  const int ti = rh * 8 + ch * 4 + ((t >> 4) & 3);   // tile row block 0..15
  const int tj = t & 15;                             // tile col block 0..15
  const int i0 = ti * 8, j0 = tj * 8;
  const int offA0 = qslot(2 * ti) * 4,     offA1 = qslot(2 * ti + 1) * 4;
  const int offB0 = qslot(2 * tj) * 4,     offB1 = qslot(2 * tj + 1) * 4;

  // ---------- build: Q = g^2 * C^T C + |alpha| I, 8x8 register tiles ----------
  float acc[8][8];
  #pragma unroll
  for (int r = 0; r < 8; ++r)
    #pragma unroll
    for (int c = 0; c < 8; ++c) acc[r][c] = 0.f;

  for (int half = 0; half < 2; ++half) {
    __syncthreads();
    #pragma unroll
    for (int p = 0; p < 8; ++p) {          // stage 64 rows of C, swizzled quads
      int qq = t + 256 * p;
      int k = qq >> 5, j4 = qq & 31;
      float4 v = *(const float4*)(cb + (size_t)(half * 64 + k) * NN + j4 * 4);
      *(float4*)(cq + k * 132 + qslot(j4) * 4) = v;
    }
    __syncthreads();
    #pragma unroll 2
    for (int k = 0; k < 64; ++k) {
      const float* rp = cq + k * 132;
      float4 A0 = *(const float4*)(rp + offA0);
      float4 A1 = *(const float4*)(rp + offA1);
      float4 B0 = *(const float4*)(rp + offB0);
      float4 B1 = *(const float4*)(rp + offB1);
      float av[8] = {A0.x, A0.y, A0.z, A0.w, A1.x, A1.y, A1.z, A1.w};
      float bv[8] = {B0.x, B0.y, B0.z, B0.w, B1.x, B1.y, B1.z, B1.w};
      #pragma unroll
      for (int r = 0; r < 8; ++r)
        #pragma unroll
        for (int c = 0; c < 8; ++c)
          acc[r][c] = fmaf(av[r], bv[c], acc[r][c]);
    }
  }

  // finish Q, accumulate Frobenius^2
  float ss = 0.f;
  #pragma unroll
  for (int r = 0; r < 8; ++r)
    #pragma unroll
    for (int c = 0; c < 8; ++c) {
      float q = g2 * acc[r][c];
      if (i0 + r == j0 + c) q += aab;
      acc[r][c] = q;
      ss = fmaf(q, q, ss);
    }
  float ssw = wsum(ss);
  if (lane == 0) red[wid] = ssw;
  __syncthreads();
  const float S    = (red[0] + red[1]) + (red[2] + red[3]);
  const float step = 0.5f / sqrtf(S);      // 1 / (2*||Q||_F)
  const float sc   = 2.f * step;           // fold 2*step into Q
  const float r2a  = step * rets[b * NN + lane];        // step*rets, coord lane
  const float r2b  = step * rets[b * NN + 64 + lane];   // coord lane+64

  if (t < NN) { yL[t] = 1.f / 128.f; wLs[t] = 1.f / 128.f; }

  // ---------- redistribute Q tiles -> row-slice fragments (via cq, 2 phases) ----------
  float4 qf[16];   // Q2[row][64*ch .. +63]
  #pragma unroll
  for (int ph = 0; ph < 2; ++ph) {
    __syncthreads();
    if (rh == ph) {                    // write scaled 8x8 tile (rows 64*ph..+63)
      #pragma unroll
      for (int r = 0; r < 8; ++r) {
        int lr = (i0 & 63) + r;
        float4 lo4 = make_float4(sc*acc[r][0], sc*acc[r][1], sc*acc[r][2], sc*acc[r][3]);
        float4 hi4 = make_float4(sc*acc[r][4], sc*acc[r][5], sc*acc[r][6], sc*acc[r][7]);
        *(float4*)(cq + lr * 132 + offB0) = lo4;
        *(float4*)(cq + lr * 132 + offB1) = hi4;
      }
    }
    __syncthreads();
    if (rh == ph) {                    // read own row slice
      #pragma unroll
      for (int u = 0; u < 16; ++u)
        qf[u] = *(const float4*)(cq + lane * 132 + qslot(16 * ch + u) * 4);
    }
  }
  __syncthreads();

  // ---------- FISTA ----------
  float t_f = 1.f;
  const int ownbase = (b >> 8) & 3;    // stagger owner wave across co-resident blocks

  for (int it = 0; it < NITER; ++it) {
    // matvec partial: p = Q2[row][colhalf] . y[colhalf]   (y via LDS broadcast)
    float4 a4 = make_float4(0.f, 0.f, 0.f, 0.f);
    const float* yb = yL + 64 * ch;
    #pragma unroll
    for (int u = 0; u < 16; ++u) {
      float4 yv = *(const float4*)(yb + 4 * u);   // wave-uniform ds_read_b128
      a4.x = fmaf(qf[u].x, yv.x, a4.x);
      a4.y = fmaf(qf[u].y, yv.y, a4.y);
      a4.z = fmaf(qf[u].z, yv.z, a4.z);
      a4.w = fmaf(qf[u].w, yv.w, a4.w);
    }
    pL[ch][row] = (a4.x + a4.y) + (a4.z + a4.w);
    __syncthreads();

    if (wid == ((it + ownbase) & 3)) {
      // owner wave: full projection, 2 coords/lane (lane, lane+64)
      float y0 = yL[lane],      y1 = yL[64 + lane];
      float p0 = pL[0][lane]      + pL[1][lane];
      float p1 = pL[0][64 + lane] + pL[1][64 + lane];
      float v0 = y0 - p0 + r2a;          // v = y - step*grad
      float v1 = y1 - p1 + r2b;

      float lo = wmin(fminf(v0, v1)) - 1.0f;
      float hi = wmax(fmaxf(v0, v1));
      for (int s2 = 0; s2 < NBIS; ++s2) {
        float tau = 0.5f * (lo + hi);
        float c0 = __builtin_amdgcn_fmed3f(v0 - tau, 0.f, 1.0f);
        float c1 = __builtin_amdgcn_fmed3f(v1 - tau, 0.f, 1.0f);
        float s = wsum(c0 + c1);
        if (s > 1.f) lo = tau; else hi = tau;
      }
      float tau0 = 0.5f * (lo + hi);
      float z0 = v0 - tau0, z1 = v1 - tau0;
      bool f0 = (z0 > 0.f) && (z0 < 1.0f);
      bool f1 = (z1 > 0.f) && (z1 < 1.0f);
      bool cap0 = (z0 >= 1.0f), cap1 = (z1 >= 1.0f);
      float sfv = wsum((f0 ? v0 : 0.f) + (f1 ? v1 : 0.f));
      float cnt = wsum((f0 ? 1.f : 0.f) + (f1 ? 1.f : 0.f)
                     + 1024.f * ((cap0 ? 1.f : 0.f) + (cap1 ? 1.f : 0.f)));
      float nu = floorf(cnt * (1.f / 1024.f));
      float nf = cnt - 1024.f * nu;
      float nfree = fmaxf(nf, 1.f);
      float tau = (sfv + nu - 1.f) / nfree;     // mw = 1
      float w0 = f0 ? (v0 - tau) : (cap0 ? 1.0f : 0.f);
      float w1 = f1 ? (v1 - tau) : (cap1 ? 1.0f : 0.f);

      float tn   = 0.5f * (1.f + sqrtf(1.f + 4.f * t_f * t_f));
      float coef = (t_f - 1.f) / tn;
      float wp0 = wLs[lane], wp1 = wLs[64 + lane];
      float yn0 = w0 + coef * (w0 - wp0);
      float yn1 = w1 + coef * (w1 - wp1);
      wLs[lane] = w0;  wLs[64 + lane] = w1;
      yL[lane]  = yn0; yL[64 + lane]  = yn1;
    }
    t_f = 0.5f * (1.f + sqrtf(1.f + 4.f * t_f * t_f));  // all waves track t
    __syncthreads();
  }

  if (t < NN) out[(size_t)b * NN + t] = wLs[t];
}

extern "C" void kernel_launch(void* const* d_in, const int* in_sizes, int n_in,
                              void* d_out, int out_size, void* d_ws, size_t ws_size,
                              hipStream_t stream) {
  (void)n_in; (void)d_ws; (void)ws_size; (void)out_size;
  const float* rets = (const float*)d_in[0];
  const float* cov  = (const float*)d_in[1];
  const float* gam  = (const float*)d_in[2];
  const float* alp  = (const float*)d_in[3];
  float* out = (float*)d_out;
  const int B = in_sizes[0] / NN;   // 1024
  markowitz_kernel<<<B, 256, 0, stream>>>(rets, cov, gam, alp, out);
}